// Round 3
// baseline (132.728 us; speedup 1.0000x reference)
//
#include <hip/hip_runtime.h>
#include <cstdint>
#include <cstddef>

#define B_ 256
#define IN_ 100000
#define H_ 512
#define OUT_ 30000
#define OUTP_ 30080
#define S_ 256
#define NSTEPS 3125   // IN_/32
#define KSPLIT 64

typedef __attribute__((ext_vector_type(4))) float f32x4;
typedef __attribute__((ext_vector_type(2))) float f32x2;
typedef __attribute__((ext_vector_type(4))) int i32x4;
typedef __attribute__((ext_vector_type(8))) short short8;
typedef __attribute__((ext_vector_type(8))) unsigned short ushort8;
typedef __attribute__((ext_vector_type(4))) unsigned short ushort4_;
typedef __attribute__((ext_vector_type(2))) uint32_t uint32x2;
typedef __attribute__((ext_vector_type(4))) uint32_t uint32x4;

union U32S8 { uint32x4 u; short8 s; };

static __device__ __forceinline__ uint32_t cvtpk(float lo, float hi) {
  uint32_t r;
  asm("v_cvt_pk_bf16_f32 %0, %1, %2" : "=v"(r) : "v"(lo), "v"(hi));
  return r;
}
static __device__ __forceinline__ unsigned short f2bf(float f) {
  union { float f; uint32_t u; } c; c.f = f;
  uint32_t u = c.u;
  u += 0x7FFFu + ((u >> 16) & 1u);   // RNE
  return (unsigned short)(u >> 16);
}
static __device__ __forceinline__ float bf2f(unsigned short h) {
  union { uint32_t u; float f; } c; c.u = ((uint32_t)h) << 16;
  return c.f;
}

// Async global->LDS DMA, 16B/lane. Cannot be sunk by the compiler (LDS-write
// side effect), uses zero VGPRs for data. Round-2 post-mortem: register
// staging was silently SUNK to the use point (VGPR=108 proves the 96-reg
// pipeline never existed), collapsing pipeline distance to 0.
static __device__ __forceinline__ void gload_lds16(const float* g, float* l) {
  __builtin_amdgcn_global_load_lds((const __attribute__((address_space(1))) void*)g,
                                   (__attribute__((address_space(3))) void*)l, 16, 0, 0);
}

// Raw barrier: drain LDS ops only; in-flight DMAs survive.
#define BARRIER() { asm volatile("s_waitcnt lgkmcnt(0)" ::: "memory"); \
    __builtin_amdgcn_s_barrier(); \
    __builtin_amdgcn_sched_barrier(0); }

// Counted wait: 6 DMAs/wave/step are ALWAYS issued (tail clamps the step
// index instead of skipping, so the count is exact). vmcnt(6) = "all but the
// newest 6 done" = step-u data complete; step-(u+1)'s 6 stay in flight.
#define WAITBAR() { asm volatile("s_waitcnt vmcnt(6) lgkmcnt(0)" ::: "memory"); \
    __builtin_amdgcn_s_barrier(); \
    __builtin_amdgcn_sched_barrier(0); }

// ---------------------------------------------------------------------------
// GEMM1 split-K. Tile 256x128, 8 waves of 64x64, grid 256 (1 block/CU),
// kc-major XCD swizzle (4 nblk sharing one kc land on one XCD -> x reuse in
// that XCD's L2).
// Round-3 staging: f32 tiles in LDS via global_load_lds (async DMA), THREE
// buffers (144 KiB) -> DMA for step u+2 issued at step u, waited at step
// u+1's top: ~2 full steps of slack, no VGPR staging to sink/spill.
// bf16 conversion on the read side (2x ds_read_b128 + 4 cvtpk per fragment).
// Bank conflicts: global source chunk is pre-swizzled lc = pc ^ (row&7);
// read applies the same XOR -> each ds_read_b128 is balanced (8 lanes per
// 4-bank group = conflict-free minimum).
// ---------------------------------------------------------------------------
__global__ __launch_bounds__(512, 2) void k_gemm1(const float* __restrict__ x,
                                                  const float* __restrict__ w1,
                                                  unsigned short* __restrict__ part) {
  __shared__ alignas(16) float Af32[3][B_ * 32];    // 3 x 32 KB
  __shared__ alignas(16) float Bf32[3][128 * 32];   // 3 x 16 KB
  const int tid = threadIdx.x;
  const int d = blockIdx.x;
  const int xcd = d & 7;
  const int i = d >> 3;
  const int kc = xcd + ((i >> 2) << 3);
  const int nblk = i & 3;
  const int s0 = (kc * NSTEPS) / KSPLIT;
  const int s1 = ((kc + 1) * NSTEPS) / KSPLIT;
  const int U = s1 - s0;   // 48 or 49

  const int lane = tid & 63;
  const int wid = tid >> 6;

  // DMA source: lane l covers (row = 8*instr + (l>>3), physical chunk l&7).
  // Global column chunk is the swizzled one: lc = (l&7) ^ (l>>3)  (row&7 ==
  // l>>3 since instr rows are multiples of 8).
  const int drow = lane >> 3;
  const int lc = (lane & 7) ^ drow;
  const float* gAd = x + (size_t)(32 * wid + drow) * IN_ + (size_t)s0 * 32 + lc * 4;
  const float* gBd = w1 + (size_t)(nblk * 128 + 16 * wid + drow) * IN_ + (size_t)s0 * 32 + lc * 4;
  const int ldsA = wid * 1024;   // float index; + j*256 per instr (8 rows x 32)
  const int ldsB = wid * 512;

  const int wrow = wid >> 1;                    // 0..3  (64-row stripe)
  const int wcol = wid & 1;                     // 0..1  (64-col stripe)
  const int fr = lane & 15;
  const int fq = lane >> 4;                     // 0..3 (8-float k-slot)
  // float index of logical chunk 2fq in row (wrow*64+fr): physical = logical ^ (row&7)
  const int aOffF = (wrow * 64 + fr) * 32 + ((2 * fq) ^ (fr & 7)) * 4;
  const int bOffF = (wcol * 64 + fr) * 32 + ((2 * fq) ^ (fr & 7)) * 4;

  f32x4 zero = {0.f, 0.f, 0.f, 0.f};
  f32x4 acc[4][4];
  #pragma unroll
  for (int mf = 0; mf < 4; ++mf)
    #pragma unroll
    for (int nf = 0; nf < 4; ++nf) acc[mf][nf] = zero;

#define G1_DMA(v, DB) { \
    const int vc_ = (v) < U ? (v) : U - 1; \
    const float* ga_ = gAd + (size_t)vc_ * 32; \
    const float* gb_ = gBd + (size_t)vc_ * 32; \
    gload_lds16(ga_,                       &Af32[DB][ldsA]); \
    gload_lds16(ga_ +  8 * (size_t)IN_,    &Af32[DB][ldsA + 256]); \
    gload_lds16(ga_ + 16 * (size_t)IN_,    &Af32[DB][ldsA + 512]); \
    gload_lds16(ga_ + 24 * (size_t)IN_,    &Af32[DB][ldsA + 768]); \
    gload_lds16(gb_,                       &Bf32[DB][ldsB]); \
    gload_lds16(gb_ +  8 * (size_t)IN_,    &Bf32[DB][ldsB + 256]); }

#define G1_COMPUTE(CB) { \
    short8 af_[4], bf_[4]; \
    _Pragma("unroll") for (int mf_ = 0; mf_ < 4; ++mf_) { \
      f32x4 lo_ = *(const f32x4*)&Af32[CB][aOffF + mf_ * 512]; \
      f32x4 hi_ = *(const f32x4*)&Af32[CB][(aOffF ^ 4) + mf_ * 512]; \
      U32S8 t_; \
      t_.u[0] = cvtpk(lo_[0], lo_[1]); t_.u[1] = cvtpk(lo_[2], lo_[3]); \
      t_.u[2] = cvtpk(hi_[0], hi_[1]); t_.u[3] = cvtpk(hi_[2], hi_[3]); \
      af_[mf_] = t_.s; } \
    _Pragma("unroll") for (int nf_ = 0; nf_ < 4; ++nf_) { \
      f32x4 lo_ = *(const f32x4*)&Bf32[CB][bOffF + nf_ * 512]; \
      f32x4 hi_ = *(const f32x4*)&Bf32[CB][(bOffF ^ 4) + nf_ * 512]; \
      U32S8 t_; \
      t_.u[0] = cvtpk(lo_[0], lo_[1]); t_.u[1] = cvtpk(lo_[2], lo_[3]); \
      t_.u[2] = cvtpk(hi_[0], hi_[1]); t_.u[3] = cvtpk(hi_[2], hi_[3]); \
      bf_[nf_] = t_.s; } \
    __builtin_amdgcn_s_setprio(1); \
    _Pragma("unroll") for (int mf_ = 0; mf_ < 4; ++mf_) \
      _Pragma("unroll") for (int nf_ = 0; nf_ < 4; ++nf_) \
        acc[mf_][nf_] = __builtin_amdgcn_mfma_f32_16x16x32_bf16(af_[mf_], bf_[nf_], acc[mf_][nf_], 0, 0, 0); \
    __builtin_amdgcn_s_setprio(0); }

// One iteration: wait step v ready (vmcnt(6)+barrier; barrier also certifies
// every wave finished READING buf (v-1)%3 == (v+2)%3, so the DMA below can
// overwrite it), issue DMA for step v+2, compute step v.
#define G1_ITER(v, CB, DB) { \
    WAITBAR() \
    G1_DMA((v) + 2, DB) \
    G1_COMPUTE(CB) }

  // prologue: steps 0,1 in flight
  G1_DMA(0, 0)
  G1_DMA(1, 1)

  int u = 0;
  #pragma unroll 1
  while (u + 2 < U) {
    G1_ITER(u,     0, 2)
    G1_ITER(u + 1, 1, 0)
    G1_ITER(u + 2, 2, 1)
    u += 3;
  }
  if (u < U)     { G1_ITER(u,     0, 2) }
  if (u + 1 < U) { G1_ITER(u + 1, 1, 0) }

  unsigned short* pp = part + (size_t)kc * (B_ * H_);
  #pragma unroll
  for (int mf = 0; mf < 4; ++mf) {
    #pragma unroll
    for (int nf = 0; nf < 4; ++nf) {
      const int row0 = wrow * 64 + mf * 16 + fq * 4;
      const int col = nblk * 128 + wcol * 64 + nf * 16 + fr;
      #pragma unroll
      for (int j = 0; j < 4; ++j)
        pp[(size_t)(row0 + j) * H_ + col] = f2bf(acc[mf][nf][j]);
    }
  }
}

// ---------------------------------------------------------------------------
// h_bf16[m][n] = bf16(relu(b1[n] + sum_kc partial))
// ---------------------------------------------------------------------------
__global__ void k_reduce_h(const unsigned short* __restrict__ part,
                           const float* __restrict__ b1,
                           unsigned short* __restrict__ hbf) {
  int t = blockIdx.x * 256 + threadIdx.x;        // 0..32767
  int base = t * 4;
  int n = base & (H_ - 1);
  float a0 = b1[n], a1 = b1[n + 1], a2 = b1[n + 2], a3 = b1[n + 3];
  #pragma unroll 8
  for (int kc = 0; kc < KSPLIT; ++kc) {
    ushort4_ v = *(const ushort4_*)(part + (size_t)kc * (B_ * H_) + base);
    a0 += bf2f(v[0]); a1 += bf2f(v[1]); a2 += bf2f(v[2]); a3 += bf2f(v[3]);
  }
  ushort4_ o;
  o[0] = f2bf(fmaxf(a0, 0.f));
  o[1] = f2bf(fmaxf(a1, 0.f));
  o[2] = f2bf(fmaxf(a2, 0.f));
  o[3] = f2bf(fmaxf(a3, 0.f));
  *(ushort4_*)(hbf + base) = o;
}

// ---------------------------------------------------------------------------
// GEMM2 (256 x 128-col tile x K=512) with DIRECT codebook gather for the
// B-tile, distance-2 pipeline, fused column log_softmax.
// ---------------------------------------------------------------------------
__global__ __launch_bounds__(512, 2) void k_gemm2(const unsigned short* __restrict__ hbf,
                                                  const int* __restrict__ codes,
                                                  const float* __restrict__ cb,
                                                  const float* __restrict__ b2,
                                                  float* __restrict__ out) {
  __shared__ alignas(16) unsigned short Ab[2][B_ * 32];
  __shared__ alignas(16) unsigned short Bb[2][128 * 32];
  __shared__ float sred[4][128];
  const int tid = threadIdx.x;
  const int n0 = blockIdx.x * 128;

  // A staging: 4 threads/row, lane-contiguous 16B; rows arow2+{0,128}
  const int arow2 = tid >> 2;                   // 0..127
  const int asl2 = tid & 3;                     // 16B slot in 64B row-step
  const unsigned short* gA = hbf + (size_t)arow2 * H_ + asl2 * 8;
  const int afz2 = (arow2 >> 1) & 3;            // (row+128) invariant
  const int aslSw2 = (asl2 ^ afz2) * 8;
  const int aOffA = arow2 * 32 + aslSw2;
  const int aOffB = (arow2 + 128) * 32 + aslSw2;

  // B staging: thread -> row rb (4 threads/row), slot-quad s4 (4 codebook slots)
  const int rb = tid >> 2;
  const int s4 = tid & 3;
  const int rbo = (n0 + rb < OUT_) ? (n0 + rb) : (OUT_ - 1);
  const int* gC = codes + (size_t)rbo * S_ + s4 * 4;
  const int bOff = rb * 32 + (s4 ^ ((rb >> 1) & 3)) * 8;

  const int lane = tid & 63;
  const int wid = tid >> 6;
  const int wrow = wid >> 1;
  const int wcol = wid & 1;
  const int fr = lane & 15;
  const int fq = lane >> 4;
  const int Ra = wrow * 64 + fr;
  const int Rb = wcol * 64 + fr;
  const int aBase = Ra * 32 + (fq ^ ((Ra >> 1) & 3)) * 8;
  const int bBase = Rb * 32 + (fq ^ ((Rb >> 1) & 3)) * 8;

  f32x4 zero = {0.f, 0.f, 0.f, 0.f};
  f32x4 acc[4][4];
  #pragma unroll
  for (int mf = 0; mf < 4; ++mf)
    #pragma unroll
    for (int nf = 0; nf < 4; ++nf) acc[mf][nf] = zero;

  ushort8 Pa0, Pa1, Qa0, Qa1;
  i32x4 Pc, Qc;
  f32x2 Pg0, Pg1, Pg2, Pg3, Qg0, Qg1, Qg2, Qg3;

#define G2_IC(S, u) if ((u) < 16) { \
    S##a0 = *(const ushort8*)(gA + (size_t)(u) * 32); \
    S##a1 = *(const ushort8*)(gA + (size_t)(u) * 32 + (size_t)128 * H_); \
    S##c  = *(const i32x4*)(gC + (u) * 16); }

#define G2_IG(S, u) if ((u) < 16) { \
    const int slb_ = (u) * 16 + s4 * 4; \
    S##g0 = *(const f32x2*)(cb + ((size_t)(slb_ + 0) * 256 + (S##c[0] & 255)) * 2); \
    S##g1 = *(const f32x2*)(cb + ((size_t)(slb_ + 1) * 256 + (S##c[1] & 255)) * 2); \
    S##g2 = *(const f32x2*)(cb + ((size_t)(slb_ + 2) * 256 + (S##c[2] & 255)) * 2); \
    S##g3 = *(const f32x2*)(cb + ((size_t)(slb_ + 3) * 256 + (S##c[3] & 255)) * 2); }

#define G2_PACK(S, b) { \
    *(ushort8*)&Ab[b][aOffA] = S##a0; \
    *(ushort8*)&Ab[b][aOffB] = S##a1; \
    uint32x4 bw_; \
    bw_[0] = cvtpk(S##g0[0], S##g0[1]); bw_[1] = cvtpk(S##g1[0], S##g1[1]); \
    bw_[2] = cvtpk(S##g2[0], S##g2[1]); bw_[3] = cvtpk(S##g3[0], S##g3[1]); \
    *(uint32x4*)&Bb[b][bOff] = bw_; }

#define G2_COMPUTE(b) { \
    short8 af_[4], bf_[4]; \
    _Pragma("unroll") for (int mf_ = 0; mf_ < 4; ++mf_) af_[mf_] = *(const short8*)&Ab[b][aBase + mf_ * 512]; \
    _Pragma("unroll") for (int nf_ = 0; nf_ < 4; ++nf_) bf_[nf_] = *(const short8*)&Bb[b][bBase + nf_ * 512]; \
    __builtin_amdgcn_s_setprio(1); \
    _Pragma("unroll") for (int mf_ = 0; mf_ < 4; ++mf_) \
      _Pragma("unroll") for (int nf_ = 0; nf_ < 4; ++nf_) \
        acc[mf_][nf_] = __builtin_amdgcn_mfma_f32_16x16x32_bf16(af_[mf_], bf_[nf_], acc[mf_][nf_], 0, 0, 0); \
    __builtin_amdgcn_s_setprio(0); }

  G2_IC(P, 0)
  G2_IC(Q, 1)
  G2_IG(P, 0)
  G2_PACK(P, 0)
  BARRIER()

  #pragma unroll 1
  for (int u = 0; u < 16; u += 2) {
    G2_IC(P, u + 2)
    G2_IG(Q, u + 1)
    G2_COMPUTE(0)
    G2_PACK(Q, 1)
    BARRIER()
    G2_IC(Q, u + 3)
    G2_IG(P, u + 2)
    G2_COMPUTE(1)
    if (u + 2 < 16) { G2_PACK(P, 0) }
    BARRIER()
  }

  // ---- epilogue: + b2, then column-wise log_softmax over the 256 rows ----
  float b2v[4];
  #pragma unroll
  for (int nf = 0; nf < 4; ++nf) {
    int col = n0 + wcol * 64 + nf * 16 + fr;
    b2v[nf] = (col < OUT_) ? b2[col] : 0.f;
  }
  #pragma unroll
  for (int mf = 0; mf < 4; ++mf)
    #pragma unroll
    for (int nf = 0; nf < 4; ++nf)
      #pragma unroll
      for (int j = 0; j < 4; ++j) acc[mf][nf][j] += b2v[nf];

  float cmax[4];
  #pragma unroll
  for (int nf = 0; nf < 4; ++nf) {
    float m = -3.4e38f;
    #pragma unroll
    for (int mf = 0; mf < 4; ++mf)
      #pragma unroll
      for (int j = 0; j < 4; ++j) m = fmaxf(m, acc[mf][nf][j]);
    m = fmaxf(m, __shfl_xor(m, 16, 64));
    m = fmaxf(m, __shfl_xor(m, 32, 64));
    cmax[nf] = m;
  }
  if (lane < 16) {
    #pragma unroll
    for (int nf = 0; nf < 4; ++nf) sred[wrow][wcol * 64 + nf * 16 + lane] = cmax[nf];
  }
  __syncthreads();
  float cm[4];
  #pragma unroll
  for (int nf = 0; nf < 4; ++nf) {
    int ci = wcol * 64 + nf * 16 + fr;
    cm[nf] = fmaxf(fmaxf(sred[0][ci], sred[1][ci]), fmaxf(sred[2][ci], sred[3][ci]));
  }
  __syncthreads();

  float cs[4];
  #pragma unroll
  for (int nf = 0; nf < 4; ++nf) {
    float sum = 0.f;
    #pragma unroll
    for (int mf = 0; mf < 4; ++mf)
      #pragma unroll
      for (int j = 0; j < 4; ++j) sum += expf(acc[mf][nf][j] - cm[nf]);
    sum += __shfl_xor(sum, 16, 64);
    sum += __shfl_xor(sum, 32, 64);
    cs[nf] = sum;
  }
  if (lane < 16) {
    #pragma unroll
    for (int nf = 0; nf < 4; ++nf) sred[wrow][wcol * 64 + nf * 16 + lane] = cs[nf];
  }
  __syncthreads();
  float lden[4];
  #pragma unroll
  for (int nf = 0; nf < 4; ++nf) {
    int ci = wcol * 64 + nf * 16 + fr;
    lden[nf] = logf(sred[0][ci] + sred[1][ci] + sred[2][ci] + sred[3][ci]);
  }

  #pragma unroll
  for (int mf = 0; mf < 4; ++mf) {
    #pragma unroll
    for (int nf = 0; nf < 4; ++nf) {
      int col = n0 + wcol * 64 + nf * 16 + fr;
      if (col < OUT_) {
        int row0 = wrow * 64 + mf * 16 + fq * 4;
        #pragma unroll
        for (int j = 0; j < 4; ++j)
          out[(size_t)(row0 + j) * OUT_ + col] = acc[mf][nf][j] - cm[nf] - lden[nf];
      }
    }
  }
}

// ---------------------------------------------------------------------------
extern "C" void kernel_launch(void* const* d_in, const int* in_sizes, int n_in,
                              void* d_out, int out_size, void* d_ws, size_t ws_size,
                              hipStream_t stream) {
  const float* x      = (const float*)d_in[0];
  const float* w1     = (const float*)d_in[1];
  const float* b1     = (const float*)d_in[2];
  const float* cb     = (const float*)d_in[3];
  const int*   codes  = (const int*)d_in[4];
  const float* b2     = (const float*)d_in[5];
  float* out = (float*)d_out;

  char* ws = (char*)d_ws;
  unsigned short* part = (unsigned short*)ws;                          // 16.8 MB
  unsigned short* hbf  = (unsigned short*)(ws + (size_t)KSPLIT * B_ * H_ * 2);

  hipLaunchKernelGGL(k_gemm1,    dim3(4 * KSPLIT),          dim3(512), 0, stream, x, w1, part);
  hipLaunchKernelGGL(k_reduce_h, dim3((B_ * H_ / 4) / 256), dim3(256), 0, stream, part, b1, hbf);
  hipLaunchKernelGGL(k_gemm2,    dim3(OUTP_ / 128),         dim3(512), 0, stream, hbf, codes, cb, b2, out);
}

// Round 5
// 119.815 us; speedup vs baseline: 1.1078x; 1.1078x over previous
//
#include <hip/hip_runtime.h>
#include <cstdint>
#include <cstddef>

#define B_ 256
#define IN_ 100000
#define H_ 512
#define OUT_ 30000
#define OUTP_ 30080
#define S_ 256
#define NSTEPS 3125   // IN_/32
#define KSPLIT 64

typedef __attribute__((ext_vector_type(4))) float f32x4;
typedef __attribute__((ext_vector_type(2))) float f32x2;
typedef __attribute__((ext_vector_type(4))) int i32x4;
typedef __attribute__((ext_vector_type(8))) short short8;
typedef __attribute__((ext_vector_type(8))) unsigned short ushort8;
typedef __attribute__((ext_vector_type(4))) unsigned short ushort4_;
typedef __attribute__((ext_vector_type(2))) uint32_t uint32x2;
typedef __attribute__((ext_vector_type(4))) uint32_t uint32x4;

union U32S8 { uint32x4 u; short8 s; };

static __device__ __forceinline__ uint32_t cvtpk(float lo, float hi) {
  uint32_t r;
  asm("v_cvt_pk_bf16_f32 %0, %1, %2" : "=v"(r) : "v"(lo), "v"(hi));
  return r;
}
// Volatile variant: used when the inputs come from asm-volatile loads whose
// completion is only guaranteed by our own s_waitcnt (rule 18: non-volatile
// ops can be hoisted past an inline-asm waitcnt; volatile asm preserves
// program order among volatile asm statements).
static __device__ __forceinline__ uint32_t cvtpk_v(float lo, float hi) {
  uint32_t r;
  asm volatile("v_cvt_pk_bf16_f32 %0, %1, %2" : "=v"(r) : "v"(lo), "v"(hi));
  return r;
}
static __device__ __forceinline__ unsigned short f2bf(float f) {
  union { float f; uint32_t u; } c; c.f = f;
  uint32_t u = c.u;
  u += 0x7FFFu + ((u >> 16) & 1u);   // RNE
  return (unsigned short)(u >> 16);
}
static __device__ __forceinline__ float bf2f(unsigned short h) {
  union { uint32_t u; float f; } c; c.u = ((uint32_t)h) << 16;
  return c.f;
}
static __device__ __forceinline__ void pack4_store(unsigned short* dst, f32x4 a) {
  uint32x2 v;
  v[0] = cvtpk(a[0], a[1]); v[1] = cvtpk(a[2], a[3]);
  *(uint32x2*)dst = v;
}
static __device__ __forceinline__ void pack4_store_v(unsigned short* dst, f32x4 a) {
  uint32x2 v;
  v[0] = cvtpk_v(a[0], a[1]); v[1] = cvtpk_v(a[2], a[3]);
  *(uint32x2*)dst = v;
}

// Sink-proof staging load: inline-asm volatile global_load_dwordx4. The
// round-2 lesson: C-level register staging gets silently SUNK to the use
// point (VGPR=108 proved the pipeline never existed). asm volatile cannot be
// sunk or reordered w.r.t. other volatile asm (our waitcnts/barriers).
#define GLOAD16(dst, ptr) \
  asm volatile("global_load_dwordx4 %0, %1, off" : "=&v"(dst) : "v"(ptr) : "memory")

// Raw barrier: drain LDS ops only; in-flight global loads survive.
#define BARRIER() { asm volatile("s_waitcnt lgkmcnt(0)" ::: "memory"); \
    __builtin_amdgcn_s_barrier(); \
    __builtin_amdgcn_sched_barrier(0); }

// Counted wait: every ISSUE adds exactly 12 loads (tail clamps the step
// index, so the count is uniform). vmcnt(12) = oldest set complete, newest
// set still in flight.
#define WAITV() { asm volatile("s_waitcnt vmcnt(12)" ::: "memory"); \
    __builtin_amdgcn_sched_barrier(0); }

// ---------------------------------------------------------------------------
// GEMM1 split-K. Tile 256x128, 8 waves of 64x64, grid 256, kc-major XCD
// swizzle. Round-4/5 structure: BK=64 (256-B contiguous per row per step —
// 2x coarser global segments, half the request count; theory: all four
// prior structures tied at ~124us = 307 MB compulsory L2-fill / ~2.5 TB/s,
// a request-granularity cap, since m13 streams 6.3 TB/s on the same path).
// Staging: asm-volatile global_load_dwordx4 -> registers -> cvtpk -> bf16
// LDS (2 buffers, 96 KB). Counted vmcnt(12), distance-2 sets.
// U in {48,49}: exactly 24 uniform BK-64 steps for ALL blocks; odd chunk
// (when U=49) handled by a register-direct MFMA mini-step (no LDS).
// (Round-4 submission failed to compile: PACKB's buffer param was named `b`
// and got pasted into S##b##i -> P01. Params renamed to BUF.)
// ---------------------------------------------------------------------------
__global__ __launch_bounds__(512, 2) void k_gemm1(const float* __restrict__ x,
                                                  const float* __restrict__ w1,
                                                  unsigned short* __restrict__ part) {
  __shared__ alignas(16) unsigned short Ab[2][B_ * 64];    // 32 KB each
  __shared__ alignas(16) unsigned short Bb[2][128 * 64];   // 16 KB each
  const int tid = threadIdx.x;
  const int d = blockIdx.x;
  const int xcd = d & 7;
  const int i = d >> 3;
  const int kc = xcd + ((i >> 2) << 3);
  const int nblk = i & 3;
  const int s0 = (kc * NSTEPS) / KSPLIT;
  const int s1 = ((kc + 1) * NSTEPS) / KSPLIT;
  // s1-s0 in {48,49}; main loop covers chunks s0..s0+47 as 24 BK-64 steps.

  const int lane = tid & 63;
  const int wid = tid >> 6;
  const int g = lane >> 4;          // 0..3: row within 4-row load group
  const int h = lane & 15;          // 16 lanes x 16 B = 256-B row chunk

  // Load mapping (per step): A = 256 rows x 256 B; wave w covers rows
  // 32w..32w+31 via 8 instrs (4 rows each). B = 128 rows; 4 instrs.
  const float* gAb = x  + (size_t)(32 * wid + g) * IN_ + (size_t)s0 * 32 + h * 4;
  const float* gBb = w1 + (size_t)(nblk * 128 + 16 * wid + g) * IN_ + (size_t)s0 * 32 + h * 4;

  const int wrow = wid >> 1;                    // 0..3  (64-row stripe)
  const int wcol = wid & 1;                     // 0..1  (64-col stripe)
  const int fr = lane & 15;
  const int fq = lane >> 4;                     // 0..3 (8-bf16 k-slot)

  f32x4 zero = {0.f, 0.f, 0.f, 0.f};
  f32x4 acc[4][4];
  #pragma unroll
  for (int mf = 0; mf < 4; ++mf)
    #pragma unroll
    for (int nf = 0; nf < 4; ++nf) acc[mf][nf] = zero;

  f32x4 Pa0, Pa1, Pa2, Pa3, Pa4, Pa5, Pa6, Pa7, Pb0, Pb1, Pb2, Pb3;
  f32x4 Qa0, Qa1, Qa2, Qa3, Qa4, Qa5, Qa6, Qa7, Qb0, Qb1, Qb2, Qb3;

#define G1_ISSUE(S, v) { \
    const size_t o_ = (size_t)(((v) < 24) ? (v) : 23) * 64; \
    GLOAD16(S##a0, gAb + o_); \
    GLOAD16(S##a1, gAb + o_ +  4 * (size_t)IN_); \
    GLOAD16(S##a2, gAb + o_ +  8 * (size_t)IN_); \
    GLOAD16(S##a3, gAb + o_ + 12 * (size_t)IN_); \
    GLOAD16(S##a4, gAb + o_ + 16 * (size_t)IN_); \
    GLOAD16(S##a5, gAb + o_ + 20 * (size_t)IN_); \
    GLOAD16(S##a6, gAb + o_ + 24 * (size_t)IN_); \
    GLOAD16(S##a7, gAb + o_ + 28 * (size_t)IN_); \
    GLOAD16(S##b0, gBb + o_); \
    GLOAD16(S##b1, gBb + o_ +  4 * (size_t)IN_); \
    GLOAD16(S##b2, gBb + o_ +  8 * (size_t)IN_); \
    GLOAD16(S##b3, gBb + o_ + 12 * (size_t)IN_); }

// LDS row = 64 bf16 = 128 B = 8 x 16-B chunks; physical chunk = logical ^
// (row&7) (same family as round 2, which measured ZERO bank conflicts).
// NOTE: buffer param is named BUF (NOT a/b) because the ## operands must be
// literal tokens: S##a##i / S##b##i.
#define PACKA(S, BUF, i) { const int r_ = 32 * wid + 4 * (i) + g; \
    pack4_store_v(&Ab[BUF][r_ * 64 + (((h >> 1) ^ (r_ & 7)) << 3) + ((h & 1) << 2)], S##a##i); }
#define PACKB(S, BUF, i) { const int r_ = 16 * wid + 4 * (i) + g; \
    pack4_store_v(&Bb[BUF][r_ * 64 + (((h >> 1) ^ (r_ & 7)) << 3) + ((h & 1) << 2)], S##b##i); }
#define G1_PACKALL(S, BUF) { \
    PACKA(S, BUF, 0) PACKA(S, BUF, 1) PACKA(S, BUF, 2) PACKA(S, BUF, 3) \
    PACKA(S, BUF, 4) PACKA(S, BUF, 5) PACKA(S, BUF, 6) PACKA(S, BUF, 7) \
    PACKB(S, BUF, 0) PACKB(S, BUF, 1) PACKB(S, BUF, 2) PACKB(S, BUF, 3) }

#define G1_COMPUTE(CB) { \
    _Pragma("unroll") for (int kh_ = 0; kh_ < 2; ++kh_) { \
      short8 af_[4], bf_[4]; \
      _Pragma("unroll") for (int mf_ = 0; mf_ < 4; ++mf_) { \
        const int R_ = wrow * 64 + mf_ * 16 + fr; \
        af_[mf_] = *(const short8*)&Ab[CB][R_ * 64 + (((kh_ * 4 + fq) ^ (R_ & 7)) << 3)]; } \
      _Pragma("unroll") for (int nf_ = 0; nf_ < 4; ++nf_) { \
        const int R_ = wcol * 64 + nf_ * 16 + fr; \
        bf_[nf_] = *(const short8*)&Bb[CB][R_ * 64 + (((kh_ * 4 + fq) ^ (R_ & 7)) << 3)]; } \
      __builtin_amdgcn_s_setprio(1); \
      _Pragma("unroll") for (int mf_ = 0; mf_ < 4; ++mf_) \
        _Pragma("unroll") for (int nf_ = 0; nf_ < 4; ++nf_) \
          acc[mf_][nf_] = __builtin_amdgcn_mfma_f32_16x16x32_bf16(af_[mf_], bf_[nf_], acc[mf_][nf_], 0, 0, 0); \
      __builtin_amdgcn_s_setprio(0); } }

  // prologue: 2 sets in flight, step 0 packed
  G1_ISSUE(P, 0)
  G1_ISSUE(Q, 1)
  WAITV()
  G1_PACKALL(P, 0)
  BARRIER()

  // 12 iterations x 2 steps, uniform for all blocks (no tail guards).
  // Per half-iter: issue step v+2 (12 loads), compute step v, wait the set
  // issued last half-iter (vmcnt(12)), pack it, barrier.
  #pragma unroll 1
  for (int u = 0; u < 24; u += 2) {
    G1_ISSUE(P, u + 2)
    G1_COMPUTE(0)                  // step u
    WAITV()
    G1_PACKALL(Q, 1)               // step u+1
    BARRIER()
    G1_ISSUE(Q, u + 3)
    G1_COMPUTE(1)                  // step u+1
    WAITV()
    G1_PACKALL(P, 0)               // step u+2 (last iter: clamped dup, never computed)
    BARRIER()
  }

  // Odd-chunk mini-step (U==49): rank-32 update, register-direct fragments
  // (wave-local rows/cols, no LDS, no barrier).
  if (((s1 - s0) & 1) != 0) {
    const size_t k0 = (size_t)(s0 + 48) * 32;
    short8 af2[4], bf2[4];
    #pragma unroll
    for (int mf = 0; mf < 4; ++mf) {
      const float* p = x + (size_t)(wrow * 64 + mf * 16 + fr) * IN_ + k0 + fq * 8;
      f32x4 lo = *(const f32x4*)p, hi = *(const f32x4*)(p + 4);
      U32S8 t;
      t.u[0] = cvtpk(lo[0], lo[1]); t.u[1] = cvtpk(lo[2], lo[3]);
      t.u[2] = cvtpk(hi[0], hi[1]); t.u[3] = cvtpk(hi[2], hi[3]);
      af2[mf] = t.s;
    }
    #pragma unroll
    for (int nf = 0; nf < 4; ++nf) {
      const float* p = w1 + (size_t)(nblk * 128 + wcol * 64 + nf * 16 + fr) * IN_ + k0 + fq * 8;
      f32x4 lo = *(const f32x4*)p, hi = *(const f32x4*)(p + 4);
      U32S8 t;
      t.u[0] = cvtpk(lo[0], lo[1]); t.u[1] = cvtpk(lo[2], lo[3]);
      t.u[2] = cvtpk(hi[0], hi[1]); t.u[3] = cvtpk(hi[2], hi[3]);
      bf2[nf] = t.s;
    }
    #pragma unroll
    for (int mf = 0; mf < 4; ++mf)
      #pragma unroll
      for (int nf = 0; nf < 4; ++nf)
        acc[mf][nf] = __builtin_amdgcn_mfma_f32_16x16x32_bf16(af2[mf], bf2[nf], acc[mf][nf], 0, 0, 0);
  }

  unsigned short* pp = part + (size_t)kc * (B_ * H_);
  #pragma unroll
  for (int mf = 0; mf < 4; ++mf) {
    #pragma unroll
    for (int nf = 0; nf < 4; ++nf) {
      const int row0 = wrow * 64 + mf * 16 + fq * 4;
      const int col = nblk * 128 + wcol * 64 + nf * 16 + fr;
      #pragma unroll
      for (int j = 0; j < 4; ++j)
        pp[(size_t)(row0 + j) * H_ + col] = f2bf(acc[mf][nf][j]);
    }
  }
}

// ---------------------------------------------------------------------------
// h_bf16[m][n] = bf16(relu(b1[n] + sum_kc partial))
// ---------------------------------------------------------------------------
__global__ void k_reduce_h(const unsigned short* __restrict__ part,
                           const float* __restrict__ b1,
                           unsigned short* __restrict__ hbf) {
  int t = blockIdx.x * 256 + threadIdx.x;        // 0..32767
  int base = t * 4;
  int n = base & (H_ - 1);
  float a0 = b1[n], a1 = b1[n + 1], a2 = b1[n + 2], a3 = b1[n + 3];
  #pragma unroll 8
  for (int kc = 0; kc < KSPLIT; ++kc) {
    ushort4_ v = *(const ushort4_*)(part + (size_t)kc * (B_ * H_) + base);
    a0 += bf2f(v[0]); a1 += bf2f(v[1]); a2 += bf2f(v[2]); a3 += bf2f(v[3]);
  }
  ushort4_ o;
  o[0] = f2bf(fmaxf(a0, 0.f));
  o[1] = f2bf(fmaxf(a1, 0.f));
  o[2] = f2bf(fmaxf(a2, 0.f));
  o[3] = f2bf(fmaxf(a3, 0.f));
  *(ushort4_*)(hbf + base) = o;
}

// ---------------------------------------------------------------------------
// GEMM2 (256 x 128-col tile x K=512) with DIRECT codebook gather for the
// B-tile, distance-2 pipeline, fused column log_softmax.
// ---------------------------------------------------------------------------
__global__ __launch_bounds__(512, 2) void k_gemm2(const unsigned short* __restrict__ hbf,
                                                  const int* __restrict__ codes,
                                                  const float* __restrict__ cb,
                                                  const float* __restrict__ b2,
                                                  float* __restrict__ out) {
  __shared__ alignas(16) unsigned short Ab[2][B_ * 32];
  __shared__ alignas(16) unsigned short Bb[2][128 * 32];
  __shared__ float sred[4][128];
  const int tid = threadIdx.x;
  const int n0 = blockIdx.x * 128;

  // A staging: 4 threads/row, lane-contiguous 16B; rows arow2+{0,128}
  const int arow2 = tid >> 2;                   // 0..127
  const int asl2 = tid & 3;                     // 16B slot in 64B row-step
  const unsigned short* gA = hbf + (size_t)arow2 * H_ + asl2 * 8;
  const int afz2 = (arow2 >> 1) & 3;            // (row+128) invariant
  const int aslSw2 = (asl2 ^ afz2) * 8;
  const int aOffA = arow2 * 32 + aslSw2;
  const int aOffB = (arow2 + 128) * 32 + aslSw2;

  // B staging: thread -> row rb (4 threads/row), slot-quad s4 (4 codebook slots)
  const int rb = tid >> 2;
  const int s4 = tid & 3;
  const int rbo = (n0 + rb < OUT_) ? (n0 + rb) : (OUT_ - 1);
  const int* gC = codes + (size_t)rbo * S_ + s4 * 4;
  const int bOff = rb * 32 + (s4 ^ ((rb >> 1) & 3)) * 8;

  const int lane = tid & 63;
  const int wid = tid >> 6;
  const int wrow = wid >> 1;
  const int wcol = wid & 1;
  const int fr = lane & 15;
  const int fq = lane >> 4;
  const int Ra = wrow * 64 + fr;
  const int Rb = wcol * 64 + fr;
  const int aBase = Ra * 32 + (fq ^ ((Ra >> 1) & 3)) * 8;
  const int bBase = Rb * 32 + (fq ^ ((Rb >> 1) & 3)) * 8;

  f32x4 zero = {0.f, 0.f, 0.f, 0.f};
  f32x4 acc[4][4];
  #pragma unroll
  for (int mf = 0; mf < 4; ++mf)
    #pragma unroll
    for (int nf = 0; nf < 4; ++nf) acc[mf][nf] = zero;

  ushort8 Pa0, Pa1, Qa0, Qa1;
  i32x4 Pc, Qc;
  f32x2 Pg0, Pg1, Pg2, Pg3, Qg0, Qg1, Qg2, Qg3;

#define G2_IC(S, u) if ((u) < 16) { \
    S##a0 = *(const ushort8*)(gA + (size_t)(u) * 32); \
    S##a1 = *(const ushort8*)(gA + (size_t)(u) * 32 + (size_t)128 * H_); \
    S##c  = *(const i32x4*)(gC + (u) * 16); }

#define G2_IG(S, u) if ((u) < 16) { \
    const int slb_ = (u) * 16 + s4 * 4; \
    S##g0 = *(const f32x2*)(cb + ((size_t)(slb_ + 0) * 256 + (S##c[0] & 255)) * 2); \
    S##g1 = *(const f32x2*)(cb + ((size_t)(slb_ + 1) * 256 + (S##c[1] & 255)) * 2); \
    S##g2 = *(const f32x2*)(cb + ((size_t)(slb_ + 2) * 256 + (S##c[2] & 255)) * 2); \
    S##g3 = *(const f32x2*)(cb + ((size_t)(slb_ + 3) * 256 + (S##c[3] & 255)) * 2); }

#define G2_PACK(S, BUF) { \
    *(ushort8*)&Ab[BUF][aOffA] = S##a0; \
    *(ushort8*)&Ab[BUF][aOffB] = S##a1; \
    uint32x4 bw_; \
    bw_[0] = cvtpk(S##g0[0], S##g0[1]); bw_[1] = cvtpk(S##g1[0], S##g1[1]); \
    bw_[2] = cvtpk(S##g2[0], S##g2[1]); bw_[3] = cvtpk(S##g3[0], S##g3[1]); \
    *(uint32x4*)&Bb[BUF][bOff] = bw_; }

#define G2_COMPUTE(BUF) { \
    short8 af_[4], bf_[4]; \
    _Pragma("unroll") for (int mf_ = 0; mf_ < 4; ++mf_) af_[mf_] = *(const short8*)&Ab[BUF][aBase + mf_ * 512]; \
    _Pragma("unroll") for (int nf_ = 0; nf_ < 4; ++nf_) bf_[nf_] = *(const short8*)&Bb[BUF][bBase + nf_ * 512]; \
    __builtin_amdgcn_s_setprio(1); \
    _Pragma("unroll") for (int mf_ = 0; mf_ < 4; ++mf_) \
      _Pragma("unroll") for (int nf_ = 0; nf_ < 4; ++nf_) \
        acc[mf_][nf_] = __builtin_amdgcn_mfma_f32_16x16x32_bf16(af_[mf_], bf_[nf_], acc[mf_][nf_], 0, 0, 0); \
    __builtin_amdgcn_s_setprio(0); }

  G2_IC(P, 0)
  G2_IC(Q, 1)
  G2_IG(P, 0)
  G2_PACK(P, 0)
  BARRIER()

  #pragma unroll 1
  for (int u = 0; u < 16; u += 2) {
    G2_IC(P, u + 2)
    G2_IG(Q, u + 1)
    G2_COMPUTE(0)
    G2_PACK(Q, 1)
    BARRIER()
    G2_IC(Q, u + 3)
    G2_IG(P, u + 2)
    G2_COMPUTE(1)
    if (u + 2 < 16) { G2_PACK(P, 0) }
    BARRIER()
  }

  // ---- epilogue: + b2, then column-wise log_softmax over the 256 rows ----
  float b2v[4];
  #pragma unroll
  for (int nf = 0; nf < 4; ++nf) {
    int col = n0 + wcol * 64 + nf * 16 + fr;
    b2v[nf] = (col < OUT_) ? b2[col] : 0.f;
  }
  #pragma unroll
  for (int mf = 0; mf < 4; ++mf)
    #pragma unroll
    for (int nf = 0; nf < 4; ++nf)
      #pragma unroll
      for (int j = 0; j < 4; ++j) acc[mf][nf][j] += b2v[nf];

  float cmax[4];
  #pragma unroll
  for (int nf = 0; nf < 4; ++nf) {
    float m = -3.4e38f;
    #pragma unroll
    for (int mf = 0; mf < 4; ++mf)
      #pragma unroll
      for (int j = 0; j < 4; ++j) m = fmaxf(m, acc[mf][nf][j]);
    m = fmaxf(m, __shfl_xor(m, 16, 64));
    m = fmaxf(m, __shfl_xor(m, 32, 64));
    cmax[nf] = m;
  }
  if (lane < 16) {
    #pragma unroll
    for (int nf = 0; nf < 4; ++nf) sred[wrow][wcol * 64 + nf * 16 + lane] = cmax[nf];
  }
  __syncthreads();
  float cm[4];
  #pragma unroll
  for (int nf = 0; nf < 4; ++nf) {
    int ci = wcol * 64 + nf * 16 + fr;
    cm[nf] = fmaxf(fmaxf(sred[0][ci], sred[1][ci]), fmaxf(sred[2][ci], sred[3][ci]));
  }
  __syncthreads();

  float cs[4];
  #pragma unroll
  for (int nf = 0; nf < 4; ++nf) {
    float sum = 0.f;
    #pragma unroll
    for (int mf = 0; mf < 4; ++mf)
      #pragma unroll
      for (int j = 0; j < 4; ++j) sum += expf(acc[mf][nf][j] - cm[nf]);
    sum += __shfl_xor(sum, 16, 64);
    sum += __shfl_xor(sum, 32, 64);
    cs[nf] = sum;
  }
  if (lane < 16) {
    #pragma unroll
    for (int nf = 0; nf < 4; ++nf) sred[wrow][wcol * 64 + nf * 16 + lane] = cs[nf];
  }
  __syncthreads();
  float lden[4];
  #pragma unroll
  for (int nf = 0; nf < 4; ++nf) {
    int ci = wcol * 64 + nf * 16 + fr;
    lden[nf] = logf(sred[0][ci] + sred[1][ci] + sred[2][ci] + sred[3][ci]);
  }

  #pragma unroll
  for (int mf = 0; mf < 4; ++mf) {
    #pragma unroll
    for (int nf = 0; nf < 4; ++nf) {
      int col = n0 + wcol * 64 + nf * 16 + fr;
      if (col < OUT_) {
        int row0 = wrow * 64 + mf * 16 + fq * 4;
        #pragma unroll
        for (int j = 0; j < 4; ++j)
          out[(size_t)(row0 + j) * OUT_ + col] = acc[mf][nf][j] - cm[nf] - lden[nf];
      }
    }
  }
}

// ---------------------------------------------------------------------------
extern "C" void kernel_launch(void* const* d_in, const int* in_sizes, int n_in,
                              void* d_out, int out_size, void* d_ws, size_t ws_size,
                              hipStream_t stream) {
  const float* x      = (const float*)d_in[0];
  const float* w1     = (const float*)d_in[1];
  const float* b1     = (const float*)d_in[2];
  const float* cb     = (const float*)d_in[3];
  const int*   codes  = (const int*)d_in[4];
  const float* b2     = (const float*)d_in[5];
  float* out = (float*)d_out;

  char* ws = (char*)d_ws;
  unsigned short* part = (unsigned short*)ws;                          // 16.8 MB
  unsigned short* hbf  = (unsigned short*)(ws + (size_t)KSPLIT * B_ * H_ * 2);

  hipLaunchKernelGGL(k_gemm1,    dim3(4 * KSPLIT),          dim3(512), 0, stream, x, w1, part);
  hipLaunchKernelGGL(k_reduce_h, dim3((B_ * H_ / 4) / 256), dim3(256), 0, stream, part, b1, hbf);
  hipLaunchKernelGGL(k_gemm2,    dim3(OUTP_ / 128),         dim3(512), 0, stream, hbf, codes, cb, b2, out);
}